// Round 5
// baseline (86.166 us; speedup 1.0000x reference)
//
#include <hip/hip_runtime.h>
#include <hip/hip_bf16.h>
#include <stdint.h>

#define NN    4096
#define INF_  256
#define HEADS 4
#define HID   64
#define OUTC  256
#define NEG   0.2f
#define L2E   1.44269504f

#define BI     32
#define JSPLIT 8
#define NJ     (NN / JSPLIT)

typedef short bf16x8 __attribute__((ext_vector_type(8)));
typedef float f32x4  __attribute__((ext_vector_type(4)));

// ---- float <-> order-preserving uint encoding (for atomicMax on f32) ----
__device__ __forceinline__ uint32_t ford(float x){
  uint32_t u = __float_as_uint(x);
  return (u & 0x80000000u) ? ~u : (u | 0x80000000u);
}
__device__ __forceinline__ float funord(uint32_t e){
  uint32_t u = (e & 0x80000000u) ? (e & 0x7fffffffu) : ~e;
  return __uint_as_float(u);
}
__device__ __forceinline__ ushort bf16u(float f){
  __hip_bfloat16 b = __float2bfloat16(f);
  return *reinterpret_cast<ushort*>(&b);
}

// ---- adjacency int32 [4096][4096] -> bitmask [4096][128] uint32 ----
__global__ void k_pack(const int* __restrict__ adj, uint32_t* __restrict__ bm){
  __shared__ ushort sh[256];
  int i = blockIdx.x;
  int t = threadIdx.x;
  const int* row = adj + (size_t)i*NN + t*16;
  uint32_t b = 0;
  #pragma unroll
  for (int u = 0; u < 4; u++){
    int4 v = *(const int4*)(row + u*4);
    b |= (v.x ? 1u : 0u) << (u*4 + 0);
    b |= (v.y ? 1u : 0u) << (u*4 + 1);
    b |= (v.z ? 1u : 0u) << (u*4 + 2);
    b |= (v.w ? 1u : 0u) << (u*4 + 3);
  }
  sh[t] = (ushort)b;
  __syncthreads();
  if (t < 128)
    bm[(size_t)i*128 + t] = (uint32_t)sh[2*t] | ((uint32_t)sh[2*t + 1] << 16);
}

// ---- W f32 -> bf16 hi/lo split ----
__global__ void w_cvt(const float* __restrict__ W, short* __restrict__ whi,
                      short* __restrict__ wlo){
  int idx = (blockIdx.x*256 + threadIdx.x)*4;
  float4 v = *(const float4*)&W[idx];
  float av[4] = {v.x, v.y, v.z, v.w};
  ushort hiu[4], lou[4];
  #pragma unroll
  for (int q = 0; q < 4; q++){
    ushort hv = bf16u(av[q]);
    float xh = __uint_as_float(((uint32_t)hv) << 16);
    hiu[q] = hv;
    lou[q] = bf16u(av[q] - xh);
  }
  *(uint2*)&whi[idx] = *(uint2*)hiu;
  *(uint2*)&wlo[idx] = *(uint2*)lou;
}

// ---- g = h @ W^T via 3-product bf16-split MFMA; emits gT bf16, scores, srmax ----
__launch_bounds__(256)
__global__ void k_gemm(const float* __restrict__ hmat, const short* __restrict__ whi,
                       const short* __restrict__ wlo, const float* __restrict__ aw,
                       short* __restrict__ gT, float* __restrict__ slT2,
                       float* __restrict__ srT2, uint32_t* __restrict__ srmax2){
  __shared__ float T[4][64*17];
  int t  = threadIdx.x;
  int hd = t >> 6, l = t & 63;
  int lr = l & 15, lg = l >> 4;
  int i0 = blockIdx.x * 16;

  const float* hp = hmat + (size_t)(i0 + lr)*INF_ + lg*8;
  size_t wofs[4];
  #pragma unroll
  for (int n = 0; n < 4; n++)
    wofs[n] = (size_t)(hd*HID + n*16 + lr)*INF_ + lg*8;

  f32x4 acc[4] = {};
  #pragma unroll
  for (int ks = 0; ks < 8; ks++){
    float4 a0 = *(const float4*)(hp + ks*32);
    float4 a1 = *(const float4*)(hp + ks*32 + 4);
    float av[8] = {a0.x, a0.y, a0.z, a0.w, a1.x, a1.y, a1.z, a1.w};
    ushort hiu[8], lou[8];
    #pragma unroll
    for (int q = 0; q < 8; q++){
      ushort hv = bf16u(av[q]);
      float xh = __uint_as_float(((uint32_t)hv) << 16);
      hiu[q] = hv;
      lou[q] = bf16u(av[q] - xh);
    }
    bf16x8 ahi = *(bf16x8*)hiu;
    bf16x8 alo = *(bf16x8*)lou;
    #pragma unroll
    for (int n = 0; n < 4; n++){
      bf16x8 bhi = *(const bf16x8*)(whi + wofs[n] + ks*32);
      bf16x8 blo = *(const bf16x8*)(wlo + wofs[n] + ks*32);
      acc[n] = __builtin_amdgcn_mfma_f32_16x16x32_bf16(ahi, bhi, acc[n], 0, 0, 0);
      acc[n] = __builtin_amdgcn_mfma_f32_16x16x32_bf16(ahi, blo, acc[n], 0, 0, 0);
      acc[n] = __builtin_amdgcn_mfma_f32_16x16x32_bf16(alo, bhi, acc[n], 0, 0, 0);
    }
  }

  // scores (log2e-scaled); acc[n][r] = g[row i0+lg*4+r][col hd*64+n*16+lr]
  float alv[4], arv[4];
  #pragma unroll
  for (int n = 0; n < 4; n++){ alv[n] = aw[n*16 + lr]; arv[n] = aw[64 + n*16 + lr]; }
  float rmax = -3.4e38f;
  #pragma unroll
  for (int r = 0; r < 4; r++){
    float slp = 0.f, srp = 0.f;
    #pragma unroll
    for (int n = 0; n < 4; n++){
      slp = fmaf(acc[n][r], alv[n], slp);
      srp = fmaf(acc[n][r], arv[n], srp);
    }
    #pragma unroll
    for (int m = 1; m < 16; m <<= 1){
      slp += __shfl_xor(slp, m, 64);
      srp += __shfl_xor(srp, m, 64);
    }
    slp *= L2E; srp *= L2E;
    if (lr == 0){
      slT2[(size_t)hd*NN + i0 + lg*4 + r] = slp;
      srT2[(size_t)hd*NN + i0 + lg*4 + r] = srp;
    }
    rmax = fmaxf(rmax, srp);
  }
  rmax = fmaxf(rmax, __shfl_xor(rmax, 16, 64));
  rmax = fmaxf(rmax, __shfl_xor(rmax, 32, 64));
  if (l == 0) atomicMax(srmax2 + hd, ford(rmax));

  // transpose acc -> gT bf16 via LDS (per-wave slice)
  #pragma unroll
  for (int n = 0; n < 4; n++)
    #pragma unroll
    for (int r = 0; r < 4; r++)
      T[hd][(n*16 + lr)*17 + lg*4 + r] = acc[n][r];
  __syncthreads();
  ushort u16[16];
  #pragma unroll
  for (int v = 0; v < 16; v++) u16[v] = bf16u(T[hd][l*17 + v]);
  *(uint4*)&gT[(size_t)(hd*HID + l)*NN + i0]     = *(uint4*)&u16[0];
  *(uint4*)&gT[(size_t)(hd*HID + l)*NN + i0 + 8] = *(uint4*)&u16[8];
}

// ---- fused masked-softmax attention; fully unrolled, den via ones-MFMA ----
__launch_bounds__(256, 4)
__global__ void k_attn(const short* __restrict__ gT, const float* __restrict__ slT2,
                       const float* __restrict__ srT2, const uint32_t* __restrict__ srmax2,
                       const uint32_t* __restrict__ bm,
                       __hip_bfloat16* __restrict__ num_p, float* __restrict__ den_p){
  __shared__ float    srs[4][512];
  __shared__ float    srs2[4][512];     // NEG * sr
  __shared__ uint32_t bmlds[32 * 17];
  int t  = threadIdx.x;
  int h  = t >> 6, l = t & 63;
  int lr = l & 15, lg = l >> 4;
  int i0 = blockIdx.x * BI;
  int jb = blockIdx.y * NJ;
  int js = blockIdx.y;

  #pragma unroll
  for (int u = 0; u < 2; u++){
    int id = t + u*256;
    int hh = id >> 7, jj = (id & 127) * 4;
    float4 v = *(const float4*)&srT2[(size_t)hh*NN + jb + jj];
    *(float4*)&srs[hh][jj]  = v;
    *(float4*)&srs2[hh][jj] = make_float4(NEG*v.x, NEG*v.y, NEG*v.z, NEG*v.w);
    int r = id >> 4, w = id & 15;
    bmlds[r*17 + w] = bm[(size_t)(i0 + r)*128 + (jb >> 5) + w];
  }

  float srmaxh = funord(srmax2[h]);
  float d1[2], d2[2];
  #pragma unroll
  for (int m = 0; m < 2; m++){
    float slv = slT2[(size_t)h*NN + i0 + m*16 + lr];
    float x   = slv + srmaxh;
    float msh = fmaxf(x, NEG * x);
    d1[m] = slv - msh;
    d2[m] = NEG * slv - msh;
  }
  __syncthreads();

  f32x4 acc[2][4] = {};
  f32x4 dacc[2]   = {};
  bf16x8 ones;
  #pragma unroll
  for (int q = 0; q < 8; q++) ones[q] = (short)0x3F80;

  const short* gTh = gT + (size_t)h*HID*NN;
  const short* bp[4];
  #pragma unroll
  for (int n = 0; n < 4; n++)
    bp[n] = gTh + (size_t)(n*16 + lr)*NN + jb + lg*8;

  bf16x8 Bb[2][4];
  #pragma unroll
  for (int n = 0; n < 4; n++){
    Bb[0][n] = *(const bf16x8*)(bp[n]);
    Bb[1][n] = *(const bf16x8*)(bp[n] + 32);
  }

  #pragma unroll
  for (int s = 0; s < 16; s++){
    float4 s0 = *(const float4*)&srs[h][s*32 + lg*8];
    float4 s1 = *(const float4*)&srs[h][s*32 + lg*8 + 4];
    float4 t0 = *(const float4*)&srs2[h][s*32 + lg*8];
    float4 t1 = *(const float4*)&srs2[h][s*32 + lg*8 + 4];
    float sr8[8]  = {s0.x, s0.y, s0.z, s0.w, s1.x, s1.y, s1.z, s1.w};
    float sr02[8] = {t0.x, t0.y, t0.z, t0.w, t1.x, t1.y, t1.z, t1.w};
    uint32_t wrd0 = bmlds[lr*17 + s];
    uint32_t wrd1 = bmlds[(16 + lr)*17 + s];

    bf16x8 A[2];
    #pragma unroll
    for (int m = 0; m < 2; m++){
      uint32_t bits = ((m ? wrd1 : wrd0) >> (lg*8)) & 0xffu;
      ushort u16[8];
      #pragma unroll
      for (int q = 0; q < 8; q++){
        float e2 = fmaxf(d1[m] + sr8[q], d2[m] + sr02[q]);
        float wv = __builtin_amdgcn_exp2f(e2);
        wv = (bits & (1u << q)) ? wv : 0.f;
        u16[q] = bf16u(wv);
      }
      A[m] = *(bf16x8*)u16;
    }

    #pragma unroll
    for (int m = 0; m < 2; m++){
      dacc[m] = __builtin_amdgcn_mfma_f32_16x16x32_bf16(A[m], ones, dacc[m], 0, 0, 0);
      #pragma unroll
      for (int n = 0; n < 4; n++)
        acc[m][n] = __builtin_amdgcn_mfma_f32_16x16x32_bf16(A[m], Bb[s & 1][n], acc[m][n], 0, 0, 0);
    }

    if (s + 2 < 16){
      #pragma unroll
      for (int n = 0; n < 4; n++)
        Bb[s & 1][n] = *(const bf16x8*)(bp[n] + (s + 2)*32);
    }
  }

  // num partials (bf16): row = i0+m*16+lg*4+r, col = h*64+n*16+lr
  #pragma unroll
  for (int m = 0; m < 2; m++)
    #pragma unroll
    for (int n = 0; n < 4; n++)
      #pragma unroll
      for (int r = 0; r < 4; r++)
        num_p[((size_t)js*NN + i0 + m*16 + lg*4 + r)*OUTC + h*HID + n*16 + lr] =
            __float2bfloat16(acc[m][n][r]);

  // den partials from ones-MFMA: value for row m*16+lg*4+r sits in dacc[m][r] (any lr)
  if (lr == 0)
    #pragma unroll
    for (int m = 0; m < 2; m++)
      #pragma unroll
      for (int r = 0; r < 4; r++)
        den_p[((size_t)js*4 + h)*NN + i0 + m*16 + lg*4 + r] = dacc[m][r];
}

// ---- combine partials: out = sum(num)/sum(den) ----
__global__ void k_comb(const __hip_bfloat16* __restrict__ num_p,
                       const float* __restrict__ den_p, float* __restrict__ out){
  int r = blockIdx.x, c = threadIdx.x;
  int h = c >> 6;
  float s = 0.f, d = 0.f;
  #pragma unroll
  for (int js = 0; js < JSPLIT; js++)
    s += __bfloat162float(num_p[((size_t)js*NN + r)*OUTC + c]);
  #pragma unroll
  for (int js = 0; js < JSPLIT; js++)
    d += den_p[((size_t)js*4 + h)*NN + r];
  out[(size_t)r*OUTC + c] = s / d;
}

extern "C" void kernel_launch(void* const* d_in, const int* in_sizes, int n_in,
                              void* d_out, int out_size, void* d_ws, size_t ws_size,
                              hipStream_t stream){
  const float* hmat = (const float*)d_in[0];
  const int*   adj  = (const int*)d_in[1];     // int32 layout confirmed in r1
  const float* W    = (const float*)d_in[2];
  const float* aw   = (const float*)d_in[3];
  float* out = (float*)d_out;
  char*  ws  = (char*)d_ws;

  // ws layout (bytes), total ~20.9 MB
  uint32_t* srmax2 = (uint32_t*)(ws);                      // 64 B
  float*    slT2   = (float*)(ws + 1024);                  // 64 KB
  float*    srT2   = (float*)(ws + 66560);                 // 64 KB
  short*    gT     = (short*)(ws + 132096);                // 2 MB   [256][4096] bf16
  float*    den_p  = (float*)(ws + 2229248);               // 512 KB [8][4][4096]
  __hip_bfloat16* num_p = (__hip_bfloat16*)(ws + 2753536); // 16.75 MB [8][4096][256]
  uint32_t* bmask  = (uint32_t*)(ws + 19530752);           // 2 MB   [4096][128]
  short*    whi    = (short*)(ws + 21627904);              // 128 KB
  short*    wlo    = (short*)(ws + 21758976);              // 128 KB

  hipMemsetAsync(ws, 0, 64, stream);   // srmax2 init
  hipLaunchKernelGGL(w_cvt, dim3(64), dim3(256), 0, stream, W, whi, wlo);
  hipLaunchKernelGGL(k_pack, dim3(NN), dim3(256), 0, stream, adj, bmask);
  hipLaunchKernelGGL(k_gemm, dim3(NN/16), dim3(256), 0, stream,
                     hmat, whi, wlo, aw, gT, slT2, srT2, srmax2);
  hipLaunchKernelGGL(k_attn, dim3(NN/BI, JSPLIT), dim3(256), 0, stream,
                     gT, slT2, srT2, srmax2, bmask, num_p, den_p);
  hipLaunchKernelGGL(k_comb, dim3(NN), dim3(256), 0, stream, num_p, den_p, out);
}